// Round 1
// baseline (1240.459 us; speedup 1.0000x reference)
//
#include <hip/hip_runtime.h>

// DeformConvBlock: B=4, C=64, H=W=256, OUT=64, fp32 baseline (no MFMA yet).
// Single fused kernel: phase 1 computes the 18 offset channels per pixel
// (3x3 conv), phase 2 does the 9-tap bilinear gather + 64x576 matvec.
// Block = 256 threads = one image row. LDS: per-tap weight stage (16 KB)
// + per-row offsets (18 KB).

namespace {
constexpr int B_ = 4;
constexpr int C_ = 64;
constexpr int H_ = 256;
constexpr int W_ = 256;
constexpr int OUT_ = 64;
constexpr int HW_ = H_ * W_;
}

__device__ __forceinline__ void bilin_setup(float ys, float xs, int* a, float* w)
{
    const float y0f = floorf(ys), x0f = floorf(xs);
    const float ly = ys - y0f, lx = xs - x0f;
    const int y0 = (int)y0f, x0 = (int)x0f;
    const int y1 = y0 + 1, x1 = x0 + 1;
    const int y0c = min(max(y0, 0), H_ - 1);
    const int y1c = min(max(y1, 0), H_ - 1);
    const int x0c = min(max(x0, 0), W_ - 1);
    const int x1c = min(max(x1, 0), W_ - 1);
    const float fy0 = (y0 >= 0 && y0 < H_) ? 1.0f : 0.0f;
    const float fy1 = (y1 >= 0 && y1 < H_) ? 1.0f : 0.0f;
    const float fx0 = (x0 >= 0 && x0 < W_) ? 1.0f : 0.0f;
    const float fx1 = (x1 >= 0 && x1 < W_) ? 1.0f : 0.0f;
    a[0] = y0c * W_ + x0c;  w[0] = (1.0f - ly) * (1.0f - lx) * fy0 * fx0;
    a[1] = y0c * W_ + x1c;  w[1] = (1.0f - ly) * lx          * fy0 * fx1;
    a[2] = y1c * W_ + x0c;  w[2] = ly          * (1.0f - lx) * fy1 * fx0;
    a[3] = y1c * W_ + x1c;  w[3] = ly          * lx          * fy1 * fx1;
}

__global__ __launch_bounds__(256, 3)
void deform_fused(const float* __restrict__ x,
                  const float* __restrict__ w_off,
                  const float* __restrict__ b_off,
                  const float* __restrict__ w_def,
                  const float* __restrict__ b_def,
                  float* __restrict__ out)
{
    __shared__ float off_lds[256 * 18];                 // per-pixel 18 offsets
    __shared__ __align__(16) float wstage[64 * 64];     // per-tap weight slice

    const int tid = threadIdx.x;
    const int row = blockIdx.x;          // 0 .. B*H-1
    const int b = row >> 8;              // H_ == 256
    const int y = row & 255;
    const float* __restrict__ xb = x + (size_t)b * C_ * HW_;

    // ---------------- phase 1: offset conv (thread = pixel) ----------------
    {
        const int px = tid;
        float acc[18];
#pragma unroll
        for (int j = 0; j < 18; ++j) acc[j] = b_off[j];

#pragma unroll 1
        for (int tap = 0; tap < 9; ++tap) {
            const int ki = tap / 3, kj = tap % 3;
            const int yy = y + ki - 1;
            const int xx = px + kj - 1;
            const bool valid = (yy >= 0) && (yy < H_) && (xx >= 0) && (xx < W_);
            const int aoff = valid ? (yy * W_ + xx) : 0;
            const float mask = valid ? 1.0f : 0.0f;

            __syncthreads();
            for (int i = tid; i < 18 * 64; i += 256) {
                const int j = i >> 6, c = i & 63;
                wstage[i] = w_off[(j * C_ + c) * 9 + tap];   // [j][c] layout, c contiguous
            }
            __syncthreads();

#pragma unroll 1
            for (int cg = 0; cg < 16; ++cg) {
                const float v0 = xb[(cg * 4 + 0) * HW_ + aoff] * mask;
                const float v1 = xb[(cg * 4 + 1) * HW_ + aoff] * mask;
                const float v2 = xb[(cg * 4 + 2) * HW_ + aoff] * mask;
                const float v3 = xb[(cg * 4 + 3) * HW_ + aoff] * mask;
#pragma unroll
                for (int j = 0; j < 18; ++j) {
                    const float4 w = *(const float4*)&wstage[j * 64 + cg * 4];
                    acc[j] += v0 * w.x + v1 * w.y + v2 * w.z + v3 * w.w;
                }
            }
        }
#pragma unroll
        for (int j = 0; j < 18; ++j) off_lds[px * 18 + j] = acc[j];
    }

    // ---- phase 2: thread = (pixel pair, half of outputs) ----
    const int half = tid & 1;            // 0 -> outputs 0..31, 1 -> 32..63
    const int pp = tid >> 1;             // pixel pair index
    const int xA = pp * 2;               // pixels xA, xA+1
    const int obase = half * 32;

    float accx[32], accy[32];
#pragma unroll
    for (int o = 0; o < 32; ++o) { accx[o] = 0.0f; accy[o] = 0.0f; }

#pragma unroll 1
    for (int tap = 0; tap < 9; ++tap) {
        const int ki = tap / 3, kj = tap % 3;

        __syncthreads();   // first iter also orders off_lds writes vs reads
        for (int i = tid; i < 64 * 64; i += 256) {
            const int o = i >> 6, c = i & 63;
            wstage[i] = w_def[(o * C_ + c) * 9 + tap];       // [o][c], c contiguous
        }
        __syncthreads();

        int aA[4], aB[4];
        float wA[4], wB[4];
        {
            const float oyA = off_lds[xA * 18 + tap * 2];
            const float oxA = off_lds[xA * 18 + tap * 2 + 1];
            bilin_setup((float)(y + ki - 1) + oyA, (float)(xA + kj - 1) + oxA, aA, wA);
            const float oyB = off_lds[(xA + 1) * 18 + tap * 2];
            const float oxB = off_lds[(xA + 1) * 18 + tap * 2 + 1];
            bilin_setup((float)(y + ki - 1) + oyB, (float)(xA + kj) + oxB, aB, wB);
        }

#pragma unroll 1
        for (int cg = 0; cg < 16; ++cg) {
            float va[4], vb[4];
#pragma unroll
            for (int q = 0; q < 4; ++q) {
                const float* __restrict__ p = xb + (cg * 4 + q) * HW_;
                va[q] = p[aA[0]] * wA[0] + p[aA[1]] * wA[1]
                      + p[aA[2]] * wA[2] + p[aA[3]] * wA[3];
                vb[q] = p[aB[0]] * wB[0] + p[aB[1]] * wB[1]
                      + p[aB[2]] * wB[2] + p[aB[3]] * wB[3];
            }
#pragma unroll
            for (int oo = 0; oo < 32; ++oo) {
                const float4 w = *(const float4*)&wstage[(obase + oo) * 64 + cg * 4];
                accx[oo] += va[0] * w.x + va[1] * w.y + va[2] * w.z + va[3] * w.w;
                accy[oo] += vb[0] * w.x + vb[1] * w.y + vb[2] * w.z + vb[3] * w.w;
            }
        }
    }

    // ---- epilogue: coalesced float2 stores (x-pair) ----
#pragma unroll
    for (int oo = 0; oo < 32; ++oo) {
        const int o = obase + oo;
        const float bd = b_def[o];
        float2 v = make_float2(accx[oo] + bd, accy[oo] + bd);
        *(float2*)&out[(((size_t)b * OUT_ + o) * H_ + y) * W_ + xA] = v;
    }
}

extern "C" void kernel_launch(void* const* d_in, const int* in_sizes, int n_in,
                              void* d_out, int out_size, void* d_ws, size_t ws_size,
                              hipStream_t stream)
{
    const float* x     = (const float*)d_in[0];
    const float* w_off = (const float*)d_in[1];
    const float* b_off = (const float*)d_in[2];
    const float* w_def = (const float*)d_in[3];
    const float* b_def = (const float*)d_in[4];
    float* out = (float*)d_out;

    deform_fused<<<dim3(B_ * H_), dim3(256), 0, stream>>>(
        x, w_off, b_off, w_def, b_def, out);
}